// Round 8
// baseline (2859.119 us; speedup 1.0000x reference)
//
#include <hip/hip_runtime.h>
#include <hip/hip_bf16.h>

#define N_NODES 100000
#define N_EDGES 3200000
#define D 128
#define NBKT 782        // ceil(100000/128) buckets of 128 dst nodes
#define CAPS 4608       // per-bucket capacity: mean 4093, sigma ~64 -> +8 sigma
#define EPB 6400        // edges per p1 block
#define P1B 500         // 500*6400 = 3.2M exactly
#define EPT 25          // edges per thread in p1

typedef unsigned short u16;
typedef __attribute__((ext_vector_type(8))) short bf16x8;
typedef __attribute__((ext_vector_type(4))) float f32x4;

__device__ __forceinline__ float bf2f(u16 u) {
    union { unsigned i; float f; } a; a.i = ((unsigned)u) << 16; return a.f;
}
__device__ __forceinline__ u16 f2bf(float f) {
    __hip_bfloat16 b = __float2bfloat16(f);
    return *(u16*)&b;
}

// ---- convert W to bf16 (row-major [j][k]) ----
__global__ void convert_w(const float* __restrict__ w, u16* __restrict__ wbf) {
    int i = blockIdx.x * 256 + threadIdx.x;
    wbf[i] = f2bf(w[i]);
}

// ---- p1: LDS multisplit into 782 buckets of 128 dsts ----
// Per-block global atomic is per-BUCKET (782/block, ~500 hits/counter total),
// not per-edge — avoids the round-4 contention disaster. Payload writes are
// bucket-grouped runs (coalesced by wave).
__global__ __launch_bounds__(256) void p1_multisplit(const int* __restrict__ ei,
                                                     int* __restrict__ bcnt,
                                                     unsigned* __restrict__ bbuf) {
    __shared__ unsigned s2[EPB];                 // 25.6 KB, bucket-grouped packs
    __shared__ int hist[NBKT], lbase[NBKT], cur[NBKT], gbase[NBKT];
    __shared__ int sc[256];
    int t = threadIdx.x;
    int e0 = blockIdx.x * EPB;
    for (int i = t; i < NBKT; i += 256) hist[i] = 0;
    __syncthreads();

    // phase 1: histogram over buckets (read dst only)
#pragma unroll
    for (int k = 0; k < EPT; ++k) {
        int d = ei[N_EDGES + e0 + k * 256 + t];
        atomicAdd(&hist[d >> 7], 1);
    }
    __syncthreads();

    // reserve global space per bucket
    for (int i = t; i < NBKT; i += 256) gbase[i] = atomicAdd(&bcnt[i], hist[i]);

    // blocked exclusive scan of hist (4 entries/thread)
    int v[4]; int tsum = 0;
#pragma unroll
    for (int j = 0; j < 4; ++j) {
        int idx = 4 * t + j;
        v[j] = (idx < NBKT) ? hist[idx] : 0;
        tsum += v[j];
    }
    sc[t] = tsum; __syncthreads();
    for (int o = 1; o < 256; o <<= 1) {
        int u = (t >= o) ? sc[t - o] : 0;
        __syncthreads();
        sc[t] += u;
        __syncthreads();
    }
    int run = sc[t] - tsum;
#pragma unroll
    for (int j = 0; j < 4; ++j) {
        int idx = 4 * t + j;
        if (idx < NBKT) { lbase[idx] = run; cur[idx] = run; }
        run += v[j];
    }
    __syncthreads();

    // phase 2: re-read edges (L2-hot), reorder into bucket groups in LDS
#pragma unroll
    for (int k = 0; k < EPT; ++k) {
        int i = k * 256 + t;
        int s = ei[e0 + i];
        int d = ei[N_EDGES + e0 + i];
        int p = atomicAdd(&cur[d >> 7], 1);
        s2[p] = ((unsigned)s << 7) | ((unsigned)d & 127u);
    }
    __syncthreads();

    // phase 3: write bucket-grouped runs
    int wave = t >> 6, lane = t & 63;
    for (int bkt = wave; bkt < NBKT; bkt += 4) {
        int n = hist[bkt], lb = lbase[bkt], gb = gbase[bkt];
        unsigned* dst = bbuf + (size_t)bkt * CAPS;
        for (int j = lane; j < n; j += 64) {
            int p = gb + j;
            if (p < CAPS) dst[p] = s2[lb + j];
        }
    }
}

// ---- k2: per-bucket degree count (bucket == dst range -> exact global
// in-degree), emit dinv, and convert this bucket's rows: y = dinv * x (bf16) ----
__global__ __launch_bounds__(256) void k2_count_convert(const unsigned* __restrict__ bbuf,
                                                        const int* __restrict__ bcnt,
                                                        const float* __restrict__ x,
                                                        float* __restrict__ dinv_g,
                                                        u16* __restrict__ y) {
    __shared__ int hist[128];
    __shared__ float sdinv[128];
    int b = blockIdx.x, t = threadIdx.x;
    int m = bcnt[b]; if (m > CAPS) m = CAPS;
    if (t < 128) hist[t] = 0;
    __syncthreads();
    const unsigned* eb = bbuf + (size_t)b * CAPS;
    for (int i = t; i < m; i += 256) atomicAdd(&hist[eb[i] & 127u], 1);
    __syncthreads();
    if (t < 128) {
        int node = b * 128 + t;
        float dv = rsqrtf((float)(hist[t] + 1));
        sdinv[t] = dv;
        if (node < N_NODES) dinv_g[node] = dv;
    }
    __syncthreads();
    // convert: thread t -> row t>>1, 64-dim half (t&1)
    int r = t >> 1, c0 = (t & 1) * 64;
    int node = b * 128 + r;
    if (node < N_NODES) {
        float dv = sdinv[r];
        const float4* xp = (const float4*)(x + (size_t)node * D + c0);
        uint4* yp = (uint4*)(y + (size_t)node * D + c0);
#pragma unroll
        for (int q = 0; q < 8; ++q) {
            float4 a = xp[2 * q], c = xp[2 * q + 1];
            union { u16 h[8]; uint4 v; } o;
            o.h[0] = f2bf(a.x * dv); o.h[1] = f2bf(a.y * dv);
            o.h[2] = f2bf(a.z * dv); o.h[3] = f2bf(a.w * dv);
            o.h[4] = f2bf(c.x * dv); o.h[5] = f2bf(c.y * dv);
            o.h[6] = f2bf(c.z * dv); o.h[7] = f2bf(c.w * dv);
            yp[q] = o.v;
        }
    }
}

// ---- k3: fused gather + LDS scatter-add + self-loop + MFMA GEMM + store ----
// Block = one bucket (128 dsts). acc[dst][dim] in 64 KB LDS; lane <-> dim so
// ds_add_f32 is 2-way bank (free, m136). Epilogue reuses round-7's verified
// MFMA fragment mapping, A sourced from LDS (+ self term + dinv scale).
__global__ __launch_bounds__(256) void k3_fused(const unsigned* __restrict__ bbuf,
                                                const int* __restrict__ bcnt,
                                                const u16* __restrict__ y,
                                                const float* __restrict__ dinv_g,
                                                const u16* __restrict__ wbf,
                                                const float* __restrict__ bias,
                                                float* __restrict__ out) {
    __shared__ float acc[128 * 128];   // 64 KB -> 2 blocks/CU
    int b = blockIdx.x, t = threadIdx.x;
    int wave = t >> 6, lane = t & 63;
    for (int i = t; i < 128 * 128 / 4; i += 256) {
        f32x4 z = {0.f, 0.f, 0.f, 0.f};
        ((f32x4*)acc)[i] = z;
    }
    int m = bcnt[b]; if (m > CAPS) m = CAPS;
    __syncthreads();

    const unsigned* eb = bbuf + (size_t)b * CAPS;
    // edge loop: 8 independent gathers in flight per wave
    for (int base = wave * 8; base < m; base += 32) {
        int nv = m - base; if (nv > 8) nv = 8;
        unsigned pk[8]; float v0[8], v1[8];
#pragma unroll
        for (int j = 0; j < 8; ++j) pk[j] = (j < nv) ? eb[base + j] : 0u;
#pragma unroll
        for (int j = 0; j < 8; ++j) {
            if (j < nv) {
                const u16* yr = y + (size_t)(pk[j] >> 7) * D;
                v0[j] = bf2f(yr[lane]);
                v1[j] = bf2f(yr[lane + 64]);
            }
        }
#pragma unroll
        for (int j = 0; j < 8; ++j) {
            if (j < nv) {
                int dl = (int)(pk[j] & 127u);
                atomicAdd(&acc[dl * 128 + lane], v0[j]);
                atomicAdd(&acc[dl * 128 + lane + 64], v1[j]);
            }
        }
    }
    __syncthreads();

    // epilogue: 8 row-tiles of 16; 2 per wave
    int lrow = lane & 15, quad = lane >> 4;
#pragma unroll
    for (int tt = 0; tt < 2; ++tt) {
        int r0 = (wave * 2 + tt) * 16;
        int lr = r0 + lrow;
        int anode = b * 128 + lr;
        float dn = (anode < N_NODES) ? dinv_g[anode] : 0.f;
        const u16* yr = y + (size_t)(anode < N_NODES ? anode : 0) * D;
        bf16x8 af[4];
#pragma unroll
        for (int kt = 0; kt < 4; ++kt) {
            int k0 = kt * 32 + quad * 8;
            f32x4 a0 = *(const f32x4*)&acc[lr * 128 + k0];
            f32x4 a1 = *(const f32x4*)&acc[lr * 128 + k0 + 4];
            bf16x8 a;
            a[0] = (short)f2bf((a0.x + bf2f(yr[k0 + 0])) * dn);
            a[1] = (short)f2bf((a0.y + bf2f(yr[k0 + 1])) * dn);
            a[2] = (short)f2bf((a0.z + bf2f(yr[k0 + 2])) * dn);
            a[3] = (short)f2bf((a0.w + bf2f(yr[k0 + 3])) * dn);
            a[4] = (short)f2bf((a1.x + bf2f(yr[k0 + 4])) * dn);
            a[5] = (short)f2bf((a1.y + bf2f(yr[k0 + 5])) * dn);
            a[6] = (short)f2bf((a1.z + bf2f(yr[k0 + 6])) * dn);
            a[7] = (short)f2bf((a1.w + bf2f(yr[k0 + 7])) * dn);
            af[kt] = a;
        }
#pragma unroll
        for (int jt = 0; jt < 8; ++jt) {
            int j = jt * 16 + lrow;
            f32x4 c = {0.f, 0.f, 0.f, 0.f};
#pragma unroll
            for (int kt = 0; kt < 4; ++kt) {
                int k0 = kt * 32 + quad * 8;
                bf16x8 bf = *(const bf16x8*)(wbf + (size_t)j * D + k0);
                c = __builtin_amdgcn_mfma_f32_16x16x32_bf16(af[kt], bf, c, 0, 0, 0);
            }
            float bb = bias[j];
#pragma unroll
            for (int i2 = 0; i2 < 4; ++i2) {
                int n = b * 128 + r0 + quad * 4 + i2;
                if (n < N_NODES) out[(size_t)n * D + j] = c[i2] + bb;
            }
        }
    }
    if (b == 0 && t == 0) out[(size_t)N_NODES * D] = 0.f;  // tuple scalar
}

extern "C" void kernel_launch(void* const* d_in, const int* in_sizes, int n_in,
                              void* d_out, int out_size, void* d_ws, size_t ws_size,
                              hipStream_t stream) {
    const float* x = (const float*)d_in[0];
    const int* ei = (const int*)d_in[1];
    const float* w = (const float*)d_in[2];
    const float* bias = (const float*)d_in[3];
    float* out = (float*)d_out;

    char* ws = (char*)d_ws;
    size_t o = 0;
    auto alloc = [&](size_t bytes) -> char* {
        char* p = ws + o;
        o = (o + bytes + 511) & ~(size_t)511;
        return p;
    };
    // total ws: ~40.5 MB (within the proven 41.4 MB class)
    unsigned* bbuf = (unsigned*)alloc((size_t)NBKT * CAPS * 4);  // 14.4 MB
    u16* y = (u16*)alloc((size_t)N_NODES * D * 2);               // 25.6 MB
    float* dinv = (float*)alloc((size_t)N_NODES * 4);            // 0.4 MB
    int* bcnt = (int*)alloc((size_t)NBKT * 4);                   // 3.1 KB
    u16* wbf = (u16*)alloc((size_t)D * D * 2);                   // 32 KB

    hipMemsetAsync(bcnt, 0, (size_t)NBKT * 4, stream);

    convert_w<<<D * D / 256, 256, 0, stream>>>(w, wbf);
    p1_multisplit<<<P1B, 256, 0, stream>>>(ei, bcnt, bbuf);
    k2_count_convert<<<NBKT, 256, 0, stream>>>(bbuf, bcnt, x, dinv, y);
    k3_fused<<<NBKT, 256, 0, stream>>>(bbuf, bcnt, y, dinv, wbf, bias, out);
}

// Round 9
// 348.799 us; speedup vs baseline: 8.1970x; 8.1970x over previous
//
#include <hip/hip_runtime.h>
#include <hip/hip_bf16.h>

#define N_NODES 100000
#define N_EDGES 3200000
#define D 128

typedef unsigned short u16;

// sort parameters (round-7 proven)
#define BKT_W 512                 // dst nodes per bucket
#define NBKT 196                  // ceil(100000/512)
#define NSH 8                     // shards per bucket (spreads atomic contention)
#define CAPS 2304                 // capacity per (bucket,shard); mean 2048, +5.7 sigma
#define CAPB (NSH * CAPS)         // 18432 per bucket
#define EPB 6400                  // edges per pass-1 block
#define P1B 500                   // pass-1 blocks (500*6400 = 3.2M exactly)
#define EPT 25                    // edges per thread (6400/256)

#define CY_BLOCKS 6250            // convert_y blocks (N_NODES*D/8/256)
#define CW_BLOCKS 8               // convert_w blocks (16384/2048)

typedef __attribute__((ext_vector_type(8))) short bf16x8;
typedef __attribute__((ext_vector_type(4))) float f32x4;

__device__ __forceinline__ float bf2f(u16 u) {
    union { unsigned i; float f; } a; a.i = ((unsigned)u) << 16; return a.f;
}
__device__ __forceinline__ u16 f2bf(float f) {
    __hip_bfloat16 b = __float2bfloat16(f);
    return *(u16*)&b;
}

// ---- pass 1: LDS multisplit into 196 buckets, sharded append ----
__global__ __launch_bounds__(256) void p1_multisplit(const int* __restrict__ ei,
                                                     int* __restrict__ bcnt,
                                                     unsigned* __restrict__ bbuf) {
    __shared__ unsigned s1[EPB];
    __shared__ unsigned s2[EPB];
    __shared__ int hist[NBKT], lbase[NBKT], cur[NBKT], gbase[NBKT];
    __shared__ int sc[256];
    int t = threadIdx.x, blk = blockIdx.x;
    int sh = blk & (NSH - 1);
    int e0 = blk * EPB;
    if (t < NBKT) hist[t] = 0;
    __syncthreads();

    unsigned char bk[EPT];
#pragma unroll
    for (int k = 0; k < EPT; ++k) {
        int i = k * 256 + t;
        int s = ei[e0 + i];
        int d = ei[N_EDGES + e0 + i];
        unsigned bkt = (unsigned)d >> 9;
        bk[k] = (unsigned char)bkt;
        s1[i] = ((unsigned)s << 9) | ((unsigned)d & 511u);
        atomicAdd(&hist[bkt], 1);
    }
    __syncthreads();

    if (t < NBKT) gbase[t] = atomicAdd(&bcnt[t * NSH + sh], hist[t]);

    sc[t] = (t < NBKT) ? hist[t] : 0;
    __syncthreads();
    for (int o = 1; o < 256; o <<= 1) {
        int u = (t >= o) ? sc[t - o] : 0;
        __syncthreads();
        sc[t] += u;
        __syncthreads();
    }
    if (t < NBKT) { int ex = sc[t] - hist[t]; lbase[t] = ex; cur[t] = ex; }
    __syncthreads();

#pragma unroll
    for (int k = 0; k < EPT; ++k) {
        int i = k * 256 + t;
        int p = atomicAdd(&cur[bk[k]], 1);
        s2[p] = s1[i];
    }
    __syncthreads();

    int wave = t >> 6, lane = t & 63;
    for (int bkt = wave; bkt < NBKT; bkt += 4) {
        int n = hist[bkt], lb = lbase[bkt], gb = gbase[bkt];
        unsigned* dst = bbuf + ((size_t)bkt * NSH + sh) * CAPS;
        for (int j = lane; j < n; j += 64) {
            int p = gb + j;
            if (p < CAPS) dst[p] = s2[lb + j];
        }
    }
}

// ---- pass 2: per-bucket counting sort by local node id; emits cnt/beg/dinv ----
__global__ __launch_bounds__(256) void p2_localsort(const unsigned* __restrict__ bbuf,
                                                    const int* __restrict__ bcnt,
                                                    int* __restrict__ sorted,
                                                    int* __restrict__ beg_g,
                                                    int* __restrict__ cnt_g,
                                                    float* __restrict__ dinv_g) {
    __shared__ int hist[BKT_W], cur[BKT_W], shcnt[NSH];
    __shared__ int sc[256];
    int b = blockIdx.x, t = threadIdx.x;
    if (t < NSH) { int m = bcnt[b * NSH + t]; shcnt[t] = m > CAPS ? CAPS : m; }
    hist[t] = 0; hist[t + 256] = 0;
    __syncthreads();

    for (int sh = 0; sh < NSH; ++sh) {
        int m = shcnt[sh];
        const unsigned* p = bbuf + ((size_t)b * NSH + sh) * CAPS;
        for (int i = t; i < m; i += 256) atomicAdd(&hist[p[i] & 511u], 1);
    }
    __syncthreads();

    int a0 = hist[2 * t], a1 = hist[2 * t + 1];
    sc[t] = a0 + a1;
    __syncthreads();
    for (int o = 1; o < 256; o <<= 1) {
        int u = (t >= o) ? sc[t - o] : 0;
        __syncthreads();
        sc[t] += u;
        __syncthreads();
    }
    int exp_ = sc[t] - a0 - a1;
    cur[2 * t] = exp_;
    cur[2 * t + 1] = exp_ + a0;
    __syncthreads();

#pragma unroll
    for (int q = 0; q < 2; ++q) {
        int l = t + q * 256;
        int node = b * BKT_W + l;
        if (node < N_NODES) {
            int c = hist[l];
            cnt_g[node] = c;
            beg_g[node] = b * CAPB + cur[l];
            dinv_g[node] = rsqrtf((float)(c + 1));
        }
    }
    __syncthreads();

    int* dst = sorted + (size_t)b * CAPB;
    for (int sh = 0; sh < NSH; ++sh) {
        int m = shcnt[sh];
        const unsigned* p = bbuf + ((size_t)b * NSH + sh) * CAPS;
        for (int i = t; i < m; i += 256) {
            unsigned w = p[i];
            int pp = atomicAdd(&cur[w & 511u], 1);
            dst[pp] = (int)(w >> 9);
        }
    }
}

// ---- merged convert: blocks [0,6250) -> y = dinv*x (bf16); [6250,6258) -> wbf ----
__global__ __launch_bounds__(256) void convert_yw(const float* __restrict__ x,
                                                  const float* __restrict__ dinv,
                                                  const float* __restrict__ w,
                                                  u16* __restrict__ y,
                                                  u16* __restrict__ wbf) {
    int blk = blockIdx.x;
    if (blk < CY_BLOCKS) {
        int gid = blk * 256 + threadIdx.x;
        size_t e = (size_t)gid * 8;
        float dn = dinv[gid >> 4];
        const float4* xp = (const float4*)(x + e);
        float4 a = xp[0], b = xp[1];
        union { u16 h[8]; uint4 v; } o;
        o.h[0] = f2bf(a.x * dn); o.h[1] = f2bf(a.y * dn);
        o.h[2] = f2bf(a.z * dn); o.h[3] = f2bf(a.w * dn);
        o.h[4] = f2bf(b.x * dn); o.h[5] = f2bf(b.y * dn);
        o.h[6] = f2bf(b.z * dn); o.h[7] = f2bf(b.w * dn);
        ((uint4*)y)[gid] = o.v;
    } else {
        int idx = (blk - CY_BLOCKS) * 256 + threadIdx.x;   // 0..2047
        const float4* wp = (const float4*)(w + (size_t)idx * 8);
        float4 a = wp[0], b = wp[1];
        union { u16 h[8]; uint4 v; } o;
        o.h[0] = f2bf(a.x); o.h[1] = f2bf(a.y);
        o.h[2] = f2bf(a.z); o.h[3] = f2bf(a.w);
        o.h[4] = f2bf(b.x); o.h[5] = f2bf(b.y);
        o.h[6] = f2bf(b.z); o.h[7] = f2bf(b.w);
        ((uint4*)wbf)[idx] = o.v;
    }
}

// ---- aggregate over Y: agg[n] = dinv[n] * (y[n] + sum_{s in N(n)} y[s]) ----
// unroll 8: double the loads in flight (MLP-bound per round-7 counters).
__global__ void aggregate_y_kernel(const u16* __restrict__ y, const float* __restrict__ dinv,
                                   const int* __restrict__ beg_g, const int* __restrict__ cnt_g,
                                   const int* __restrict__ sorted_src,
                                   float* __restrict__ agg) {
    int n = blockIdx.x;
    int t = threadIdx.x;  // 0..127
    float acc = bf2f(y[(size_t)n * D + t]);  // self-loop (dinv folded into y)
    int c = cnt_g[n];
    int beg = beg_g[n];
    int i = 0;
    for (; i + 8 <= c; i += 8) {
        int s[8];
#pragma unroll
        for (int j = 0; j < 8; ++j) s[j] = sorted_src[beg + i + j];
        float v[8];
#pragma unroll
        for (int j = 0; j < 8; ++j) v[j] = bf2f(y[(size_t)s[j] * D + t]);
#pragma unroll
        for (int j = 0; j < 8; ++j) acc += v[j];
    }
    for (; i + 4 <= c; i += 4) {
        int s0 = sorted_src[beg + i];
        int s1 = sorted_src[beg + i + 1];
        int s2 = sorted_src[beg + i + 2];
        int s3 = sorted_src[beg + i + 3];
        float v0 = bf2f(y[(size_t)s0 * D + t]);
        float v1 = bf2f(y[(size_t)s1 * D + t]);
        float v2 = bf2f(y[(size_t)s2 * D + t]);
        float v3 = bf2f(y[(size_t)s3 * D + t]);
        acc += v0; acc += v1; acc += v2; acc += v3;
    }
    for (; i < c; ++i) {
        int s = sorted_src[beg + i];
        acc += bf2f(y[(size_t)s * D + t]);
    }
    agg[(size_t)n * D + t] = acc * dinv[n];
}

// ---- MFMA GEMM, in place on d_out (round-7 verified layout) ----
__global__ __launch_bounds__(256) void gemm_mfma(const u16* __restrict__ wbf,
                                                 const float* __restrict__ bias,
                                                 float* __restrict__ out) {
    int t = threadIdx.x;
    int wave = t >> 6, lane = t & 63;
    int n0 = blockIdx.x * 64 + wave * 16;
    int lrow = lane & 15;
    int quad = lane >> 4;

    int arow = n0 + lrow;
    const float* ap = out + (size_t)(arow < N_NODES ? arow : 0) * D;
    bf16x8 afrag[4];
#pragma unroll
    for (int kt = 0; kt < 4; ++kt) {
        int k0 = kt * 32 + quad * 8;
        f32x4 x0 = *(const f32x4*)(ap + k0);
        f32x4 x1 = *(const f32x4*)(ap + k0 + 4);
        bf16x8 a;
        a[0] = (short)f2bf(x0.x); a[1] = (short)f2bf(x0.y);
        a[2] = (short)f2bf(x0.z); a[3] = (short)f2bf(x0.w);
        a[4] = (short)f2bf(x1.x); a[5] = (short)f2bf(x1.y);
        a[6] = (short)f2bf(x1.z); a[7] = (short)f2bf(x1.w);
        afrag[kt] = a;
    }

#pragma unroll
    for (int jt = 0; jt < 8; ++jt) {
        int j0 = jt * 16;
        f32x4 acc = {0.f, 0.f, 0.f, 0.f};
#pragma unroll
        for (int kt = 0; kt < 4; ++kt) {
            int k0 = kt * 32 + quad * 8;
            bf16x8 b = *(const bf16x8*)(wbf + (size_t)(j0 + lrow) * D + k0);
            acc = __builtin_amdgcn_mfma_f32_16x16x32_bf16(afrag[kt], b, acc, 0, 0, 0);
        }
        float bb = bias[j0 + lrow];
#pragma unroll
        for (int i = 0; i < 4; ++i) {
            int n = n0 + quad * 4 + i;
            if (n < N_NODES) out[(size_t)n * D + j0 + lrow] = acc[i] + bb;
        }
    }
    if (blockIdx.x == 0 && t == 0) out[(size_t)N_NODES * D] = 0.f;  // tuple scalar
}

extern "C" void kernel_launch(void* const* d_in, const int* in_sizes, int n_in,
                              void* d_out, int out_size, void* d_ws, size_t ws_size,
                              hipStream_t stream) {
    const float* x = (const float*)d_in[0];
    const int* ei = (const int*)d_in[1];
    const float* w = (const float*)d_in[2];
    const float* bias = (const float*)d_in[3];
    float* out = (float*)d_out;

    char* ws = (char*)d_ws;
    size_t o = 0;
    auto alloc = [&](size_t bytes) -> char* {
        char* p = ws + o;
        o = (o + bytes + 511) & ~(size_t)511;
        return p;
    };
    // region A (25.6 MB): bbuf during sort; y (bf16) after p2 — bbuf dead then.
    char* regionA = alloc((size_t)N_NODES * D * 2);
    unsigned* bbuf = (unsigned*)regionA;
    u16* y = (u16*)regionA;
    int* sorted = (int*)alloc((size_t)NBKT * CAPB * 4);   // 14.45 MB
    int* cnt = (int*)alloc((size_t)N_NODES * 4);          // 0.4 MB
    int* beg = (int*)alloc((size_t)N_NODES * 4);          // 0.4 MB
    float* dinv = (float*)alloc((size_t)N_NODES * 4);     // 0.4 MB
    int* bcnt = (int*)alloc((size_t)NBKT * NSH * 4);      // 6.3 KB
    u16* wbf = (u16*)alloc((size_t)D * D * 2);            // 32 KB
    // total ws: ~41.4 MB (proven size class)

    hipMemsetAsync(bcnt, 0, (size_t)NBKT * NSH * 4, stream);

    p1_multisplit<<<P1B, 256, 0, stream>>>(ei, bcnt, bbuf);
    p2_localsort<<<NBKT, 256, 0, stream>>>(bbuf, bcnt, sorted, beg, cnt, dinv);
    convert_yw<<<CY_BLOCKS + CW_BLOCKS, 256, 0, stream>>>(x, dinv, w, y, wbf);
    aggregate_y_kernel<<<N_NODES, 128, 0, stream>>>(y, dinv, beg, cnt, sorted, out);
    gemm_mfma<<<(N_NODES + 63) / 64, 256, 0, stream>>>(wbf, bias, out);
}